// Round 6
// baseline (141.699 us; speedup 1.0000x reference)
//
#include <hip/hip_runtime.h>
#include <hip/hip_bf16.h>
#include <cstdint>

#define BB 64
#define NN 512
#define MM 1024
#define DD 128

typedef __bf16 bf16x8 __attribute__((ext_vector_type(8)));
typedef float f32x4 __attribute__((ext_vector_type(4)));

static __device__ __forceinline__ unsigned short f2bf(float f) {
    union { float f; unsigned int i; } v; v.f = f;
    unsigned int x = v.i;
    x += 0x7FFFu + ((x >> 16) & 1u);   // RNE
    return (unsigned short)(x >> 16);
}
// packed v_cvt_pk_bf16_f32: low = a, high = b
static __device__ __forceinline__ unsigned int f2bf2(float a, float b) {
    union { __hip_bfloat162 h; unsigned int u; } c;
    c.h = __float22bfloat162_rn(make_float2(a, b));
    return c.u;
}
// async global->LDS DMA, 16 B per lane, dest = wave-uniform base + lane*16
static __device__ __forceinline__ void async16(const void* g, void* l) {
    __builtin_amdgcn_global_load_lds(
        (const __attribute__((address_space(1))) void*)g,
        (__attribute__((address_space(3))) void*)l, 16, 0, 0);
}

// ---------- Kernel 0: W fp32 -> bf16, XOR-swizzled rows, Wu pre-scaled -------
// out[0,16384): Wu * log2(e), swizzled; out[16384,32768): Wv, swizzled.
// Swizzle: element (r,c) stored at r*128 + ((c>>3 ^ (r&7))<<3) + (c&7), so a
// linear global_load_lds copy yields conflict-free XOR-swizzled LDS reads.
__global__ __launch_bounds__(256) void wcvt_kernel(
    const float* __restrict__ Wu, const float* __restrict__ Wv,
    unsigned short* __restrict__ out)
{
    const float* W = blockIdx.x ? Wv : Wu;
    unsigned short* o = out + blockIdx.x * 16384;
    const float s = blockIdx.x ? 1.0f : 1.44269504088896f;   // log2(e) for Wu
    #pragma unroll
    for (int i = 0; i < 8; ++i) {
        int ch = i * 256 + threadIdx.x;         // 2048 chunks of 8 elems
        int r = ch >> 4, c = ch & 15;
        const float4* src = (const float4*)(W + r * 128 + c * 8);
        float4 a = src[0], b = src[1];
        uint4 v = { f2bf2(a.x * s, a.y * s), f2bf2(a.z * s, a.w * s),
                    f2bf2(b.x * s, b.y * s), f2bf2(b.z * s, b.w * s) };
        *(uint4*)&o[r * 128 + ((c ^ (r & 7)) << 3)] = v;
    }
}

// ---------- Kernel 1: merged projections -------------------------------------
// Grid 1536: blocks [0,1024) = V-type (Vp = relu(h_p Wv^T + b) -> Vp row-major
// tiles + VpT tiled), blocks [1024,1536) = C-type (Uc_scaled = relu(h_c Wu'^T
// + b') with Wu',b' pre-scaled by log2(e) -> Uc row-major bf16 + per-block
// column-sums Sigma_n Uc_scaled[n][d] f32).  proj_c moved here from attn.
__global__ __launch_bounds__(256, 4) void proj_kernel(
    const float* __restrict__ hp,
    const float* __restrict__ hc,
    const unsigned short* __restrict__ Wcv,   // [0,16384) Wu*log2e swz | Wv swz
    const float* __restrict__ Ub,
    const float* __restrict__ Vb,
    unsigned short* __restrict__ Y,           // Vp  (B,16,64,128)
    unsigned short* __restrict__ YT,          // VpT (B,16,128,64)
    unsigned short* __restrict__ Ucg,         // (B*512,128) bf16 row-major
    float* __restrict__ colsum)               // (B*8,128) f32
{
    __shared__ __align__(16) unsigned short Ws[17408];   // W | Ys+Ts/cs
    unsigned short* Ys = Ws;            // 64*128 shorts
    unsigned short* Ts = Ws + 8192;     // 128*72 shorts (V) / cs floats (C)
    const int t = threadIdx.x;
    const int lane = t & 63;
    const int wave = t >> 6;
    const int n16 = lane & 15, q = lane >> 4;
    const bool isC = blockIdx.x >= (BB * MM / 64);
    const float LOG2E = 1.44269504088896f;

    const long row0 = isC ? (long)(blockIdx.x - BB * MM / 64) * 64
                          : (long)blockIdx.x * 64;
    const float* X = isC ? hc : hp;
    const unsigned short* Wb = isC ? Wcv : (Wcv + 16384);
    const float* bias = isC ? Ub : Vb;

    // X loads FIRST (latency overlaps W DMA below)
    float4 xv[8];
    {
        const float* xrow = X + (row0 + wave * 16 + n16) * DD + q * 8;
        #pragma unroll
        for (int kk = 0; kk < 4; ++kk) {
            xv[2 * kk]     = *(const float4*)(xrow + kk * 32);
            xv[2 * kk + 1] = *(const float4*)(xrow + kk * 32 + 4);
        }
    }
    // DMA pre-swizzled bf16 W into LDS
    #pragma unroll
    for (int i = 0; i < 8; ++i)
        async16(Wb + (wave * 512 + i * 64 + lane) * 8, Ws + wave * 4096 + i * 512);
    __syncthreads();

    f32x4 acc[8];
    #pragma unroll
    for (int j = 0; j < 8; ++j) acc[j] = {0.f, 0.f, 0.f, 0.f};

    #pragma unroll
    for (int kk = 0; kk < 4; ++kk) {
        float4 x0 = xv[2 * kk], x1 = xv[2 * kk + 1];
        union { bf16x8 v; unsigned int u[4]; } a;
        a.u[0] = f2bf2(x0.x, x0.y); a.u[1] = f2bf2(x0.z, x0.w);
        a.u[2] = f2bf2(x1.x, x1.y); a.u[3] = f2bf2(x1.z, x1.w);
        #pragma unroll
        for (int j = 0; j < 8; ++j) {
            bf16x8 b = *(const bf16x8*)&Ws[(j * 16 + n16) * 128
                                           + (((q + 4 * kk) ^ (n16 & 7)) << 3)];
            acc[j] = __builtin_amdgcn_mfma_f32_16x16x32_bf16(a.v, b, acc[j], 0, 0, 0);
        }
    }

    unsigned short yb[8][4];
    float colp[8];
    #pragma unroll
    for (int j = 0; j < 8; ++j) {
        const float bv = isC ? bias[j * 16 + n16] * LOG2E : bias[j * 16 + n16];
        float y[4], s = 0.f;
        #pragma unroll
        for (int r = 0; r < 4; ++r) {
            float v = acc[j][r] + bv;
            v = v > 0.f ? v : 0.f;
            y[r] = v;
            s += v;
        }
        colp[j] = s;
        uint2 u = { f2bf2(y[0], y[1]), f2bf2(y[2], y[3]) };
        *(uint2*)&yb[j][0] = u;
    }
    __syncthreads();   // Ws reads done; reuse as Ys/Ts

    if (!isC) {
        #pragma unroll
        for (int j = 0; j < 8; ++j) {
            const int e = j * 16 + n16;
            #pragma unroll
            for (int r = 0; r < 4; ++r)
                Ys[(wave * 16 + q * 4 + r) * 128 + e] = yb[j][r];
            *(uint2*)&Ts[e * 72 + wave * 16 + q * 4] = *(uint2*)&yb[j][0];
        }
        __syncthreads();
        uint4* dstY = (uint4*)(Y + row0 * DD);
        const long b = row0 >> 10;
        const long mt = (row0 & 1023) >> 6;
        uint4* dstT = (uint4*)(YT + ((b * 16 + mt) * 128) * 64);
        #pragma unroll
        for (int i = 0; i < 4; ++i) {
            int idx = i * 256 + t;
            dstY[idx] = ((const uint4*)Ys)[idx];
            int e = idx >> 3, m = (idx & 7) * 8;
            dstT[idx] = *(const uint4*)&Ts[e * 72 + m];
        }
    } else {
        // column-sum: colp[j] covers rows (q,r) for col j*16+n16; reduce q
        #pragma unroll
        for (int j = 0; j < 8; ++j) {
            colp[j] += __shfl_xor(colp[j], 16);
            colp[j] += __shfl_xor(colp[j], 32);
        }
        float* cs = (float*)Ts;             // 512 floats
        if (q == 0) {
            #pragma unroll
            for (int j = 0; j < 8; ++j)
                cs[wave * 128 + j * 16 + n16] = colp[j];
        }
        #pragma unroll
        for (int j = 0; j < 8; ++j) {
            const int e = j * 16 + n16;
            #pragma unroll
            for (int r = 0; r < 4; ++r)
                Ys[(wave * 16 + q * 4 + r) * 128 + e] = yb[j][r];
        }
        __syncthreads();
        const int c = (int)(row0 >> 6);
        uint4* dstU = (uint4*)(Ucg + row0 * DD);
        #pragma unroll
        for (int i = 0; i < 4; ++i) {
            int idx = i * 256 + t;
            dstU[idx] = ((const uint4*)Ys)[idx];
        }
        if (t < 128)
            colsum[(long)c * DD + t] = cs[t] + cs[128 + t] + cs[256 + t] + cs[384 + t];
    }
}

// ---------- Kernel 2: bilinear attention (no projection inside) --------------
// Grid 512 = (b, nt) XCD-swizzled; 4 waves; LDS 67584 B (occupancy is
// grid-limited at 2 blocks/CU, so LDS up to ~80 KB is free).
//   buf0/1/2 [0,24576): VpT tile triple-buffer
//   Ps0 [24576,29184), Ps1 [29184,33792): double-buffered P exchange
// ONE barrier per mt (was 2): iter mt writes Ps[mt&1] while laggards of mt-1
// read Ps[(mt-1)&1] (disjoint); DMA(mt+1) targets the buffer that held tile
// mt-2, vacated by all waves before barrier(mt-1).  Counted wait: vmcnt(8)
// keeps this iter's 4 DMA + 4 A-prefetch in flight, drains DMA(mt) (older,
// in-order retire) so bR is complete when PV reads it.
static __device__ __forceinline__ void attn_iter(
    int mt, unsigned short* bD, const unsigned short* bR, unsigned short* Ps,
    const unsigned short* __restrict__ vpb,
    const unsigned short* __restrict__ vtb,
    int wave, int lane, int n16, int q, int a_off,
    const bf16x8 (&Bg)[4][4],
    bf16x8 (&aC)[4], bf16x8 (&aN)[4],
    f32x4 (&O)[8], float (&lpart)[4])
{
    const int nx = (mt + 1 > 15) ? 15 : mt + 1;   // clamp keeps vmcnt uniform
    {
        const unsigned short* st = vtb + nx * 8192;
        unsigned short* dst = bD + wave * 2048;
        #pragma unroll
        for (int i = 0; i < 4; ++i) {
            int L = wave * 256 + i * 64 + lane;
            int r = L >> 3, sc = L & 7, c = sc ^ (r & 7);
            async16(st + r * 64 + c * 8, dst + i * 512);
        }
    }
    __builtin_amdgcn_sched_barrier(0);   // DMA issues before Apf (vmcnt order)
    {
        const unsigned short* pa = vpb + nx * 8192 + a_off;
        #pragma unroll
        for (int kk = 0; kk < 4; ++kk)
            aN[kk] = *(const bf16x8*)(pa + kk * 32);
    }

    // QK (m-split): S^T rows m = wave*16+q*4+r, cols n = j*16+n16. Pure regs.
    f32x4 S[4];
    #pragma unroll
    for (int j = 0; j < 4; ++j) S[j] = {0.f, 0.f, 0.f, 0.f};
    __builtin_amdgcn_s_setprio(1);
    #pragma unroll
    for (int kk = 0; kk < 4; ++kk) {
        #pragma unroll
        for (int j = 0; j < 4; ++j)
            S[j] = __builtin_amdgcn_mfma_f32_16x16x32_bf16(aC[kk], Bg[j][kk], S[j], 0, 0, 0);
    }
    __builtin_amdgcn_s_setprio(0);

    // p = exp2(S) (Uc pre-scaled); write P[n][m] slices to Ps[mt&1]
    #pragma unroll
    for (int j = 0; j < 4; ++j) {
        float p0 = __builtin_exp2f(S[j][0]);
        float p1 = __builtin_exp2f(S[j][1]);
        float p2 = __builtin_exp2f(S[j][2]);
        float p3 = __builtin_exp2f(S[j][3]);
        lpart[j] += (p0 + p1) + (p2 + p3);
        uint2 u = { f2bf2(p0, p1), f2bf2(p2, p3) };
        *(uint2*)&Ps[(j * 16 + n16) * 72 + wave * 16 + q * 4] = u;
    }
    // single barrier per iteration
    asm volatile("s_waitcnt vmcnt(8) lgkmcnt(0)" ::: "memory");
    __builtin_amdgcn_s_barrier();
    __builtin_amdgcn_sched_barrier(0);

    // PV (n-split): O[n][d] for this wave's 16 n-rows from Ps + bR
    __builtin_amdgcn_s_setprio(1);
    #pragma unroll
    for (int kk = 0; kk < 2; ++kk) {
        bf16x8 a = *(const bf16x8*)&Ps[(wave * 16 + n16) * 72 + kk * 32 + q * 8];
        #pragma unroll
        for (int j = 0; j < 8; ++j) {
            bf16x8 bb = *(const bf16x8*)&bR[(j * 16 + n16) * 64 + ((kk * 4 + q) ^ (n16 & 7)) * 8];
            O[j] = __builtin_amdgcn_mfma_f32_16x16x32_bf16(a, bb, O[j], 0, 0, 0);
        }
    }
    __builtin_amdgcn_s_setprio(0);
}

__global__ __launch_bounds__(256, 2) void attn_kernel(
    const unsigned short* __restrict__ Ucg,   // (B*512,128) bf16, pre-scaled
    const unsigned short* __restrict__ Vp,    // (B,16,64,128) bf16 tiled
    const unsigned short* __restrict__ VpT,   // (B,16,128,64) bf16 tiled
    float* __restrict__ part)                 // (B*8,128) fp32
{
    __shared__ __align__(16) unsigned short smem[33792];   // 67584 B
    unsigned short* Ps0 = smem + 24576;
    unsigned short* Ps1 = smem + 29184;

    const int t = threadIdx.x;
    const int lane = t & 63;
    const int wave = t >> 6;
    const int n16 = lane & 15, q = lane >> 4;

    const int id = blockIdx.x;
    const int xcd = id & 7;
    const int slot = id >> 3;
    const int b = xcd * 8 + (slot >> 3);
    const int nt = slot & 7;

    const unsigned short* vpb = Vp + (long)b * MM * DD;    // 16 tiles of 8192
    const unsigned short* vtb = VpT + (long)b * MM * DD;
    const unsigned short* ucb = Ucg + ((long)b * NN + nt * 64) * DD;

    // Prologue: Bg (all 64 Uc rows) + A-frags tile 0 from global; DMA tile 0
    bf16x8 Bg[4][4];
    #pragma unroll
    for (int j = 0; j < 4; ++j)
        #pragma unroll
        for (int kk = 0; kk < 4; ++kk)
            Bg[j][kk] = *(const bf16x8*)&ucb[(j * 16 + n16) * 128 + kk * 32 + q * 8];

    const int a_off = (wave * 16 + n16) * 128 + q * 8;
    bf16x8 aA[4], aB[4];
    #pragma unroll
    for (int kk = 0; kk < 4; ++kk)
        aA[kk] = *(const bf16x8*)&vpb[a_off + kk * 32];
    {
        unsigned short* dst = smem + wave * 2048;
        #pragma unroll
        for (int i = 0; i < 4; ++i) {
            int L = wave * 256 + i * 64 + lane;
            int r = L >> 3, sc = L & 7, c = sc ^ (r & 7);
            async16(vtb + r * 64 + c * 8, dst + i * 512);
        }
    }
    asm volatile("s_waitcnt vmcnt(0) lgkmcnt(0)" ::: "memory");
    __builtin_amdgcn_s_barrier();
    __builtin_amdgcn_sched_barrier(0);

    // ---- Main loop: one barrier per mt ----
    f32x4 O[8];
    #pragma unroll
    for (int j = 0; j < 8; ++j) O[j] = {0.f, 0.f, 0.f, 0.f};
    float lpart[4] = {0.f, 0.f, 0.f, 0.f};

    unsigned short* bR = smem;            // tile mt (complete)
    unsigned short* bD = smem + 8192;     // DMA target: tile mt+1
    unsigned short* bT = smem + 16384;    // next DMA target
    #pragma unroll 1
    for (int mt = 0; mt < 16; mt += 2) {
        attn_iter(mt, bD, bR, Ps0, vpb, vtb, wave, lane, n16, q, a_off, Bg, aA, aB, O, lpart);
        unsigned short* tp = bR; bR = bD; bD = bT; bT = tp;
        attn_iter(mt + 1, bD, bR, Ps1, vpb, vtb, wave, lane, n16, q, a_off, Bg, aB, aA, O, lpart);
        tp = bR; bR = bD; bD = bT; bT = tp;
    }

    // ---- Epilogue: l reduction + weighted O reduction (Ps0 is free) ----
    #pragma unroll
    for (int j = 0; j < 4; ++j) {
        lpart[j] += __shfl_xor(lpart[j], 16);
        lpart[j] += __shfl_xor(lpart[j], 32);
    }
    float* lred = (float*)Ps0;              // 256 floats
    float* red  = lred + 256;               // 512 floats
    if (q == 0) {
        #pragma unroll
        for (int j = 0; j < 4; ++j)
            lred[wave * 64 + j * 16 + n16] = lpart[j];
    }
    __syncthreads();

    float inv[4];
    #pragma unroll
    for (int r = 0; r < 4; ++r) {
        int n = wave * 16 + q * 4 + r;
        inv[r] = 1.0f / (lred[n] + lred[64 + n] + lred[128 + n] + lred[192 + n]);
    }

    #pragma unroll
    for (int j = 0; j < 8; ++j) {
        float s = O[j][0] * inv[0] + O[j][1] * inv[1]
                + O[j][2] * inv[2] + O[j][3] * inv[3];
        s += __shfl_xor(s, 16);
        s += __shfl_xor(s, 32);
        if (q == 0)
            red[wave * 128 + j * 16 + n16] = s;
    }
    __syncthreads();
    if (t < 128) {
        float tot = red[t] + red[128 + t] + red[256 + t] + red[384 + t];
        part[(long)(b * 8 + nt) * DD + t] = tot;
    }
}

// ---------- Kernel 3: out = (Sigma part + RLN2*Sigma colsum) * q / N ---------
__global__ __launch_bounds__(256) void finalize_kernel(
    const float* __restrict__ part, const float* __restrict__ colsum,
    const float* __restrict__ qv, float* __restrict__ out)
{
    int i = blockIdx.x * 256 + threadIdx.x;     // 8192
    int b = i >> 7, d = i & 127;
    const float* p  = part   + (long)b * 8 * DD + d;
    const float* cs = colsum + (long)b * 8 * DD + d;
    float s = 0.f, u = 0.f;
    #pragma unroll
    for (int nt = 0; nt < 8; ++nt) { s += p[nt * DD]; u += cs[nt * DD]; }
    out[i] = (s + u * 0.69314718055994531f) * qv[d] * (1.0f / (float)NN);
}

extern "C" void kernel_launch(void* const* d_in, const int* in_sizes, int n_in,
                              void* d_out, int out_size, void* d_ws, size_t ws_size,
                              hipStream_t stream) {
    const float* h_c = (const float*)d_in[0];
    const float* h_p = (const float*)d_in[1];
    const float* U_w = (const float*)d_in[2];
    const float* U_b = (const float*)d_in[3];
    const float* V_w = (const float*)d_in[4];
    const float* V_b = (const float*)d_in[5];
    const float* qv  = (const float*)d_in[6];
    float* out = (float*)d_out;

    unsigned short* Vp  = (unsigned short*)d_ws;                 // (B,16,64,128) bf16
    unsigned short* VpT = Vp + (size_t)BB * MM * DD;             // (B,16,128,64) bf16
    unsigned short* Ucg = VpT + (size_t)BB * MM * DD;            // (B*512,128) bf16
    float* part   = (float*)(Ucg + (size_t)BB * NN * DD);        // (B*8,128) fp32
    float* colsum = part + (size_t)BB * 8 * DD;                  // (B*8,128) fp32
    unsigned short* Wcv = (unsigned short*)(colsum + (size_t)BB * 8 * DD); // 2x16384

    wcvt_kernel<<<2, 256, 0, stream>>>(U_w, V_w, Wcv);
    proj_kernel<<<BB * MM / 64 + BB * NN / 64, 256, 0, stream>>>(
        h_p, h_c, Wcv, U_b, V_b, Vp, VpT, Ucg, colsum);
    attn_kernel<<<512, 256, 0, stream>>>(Ucg, Vp, VpT, part);
    finalize_kernel<<<32, 256, 0, stream>>>(part, colsum, qv, out);
}

// Round 7
// 138.958 us; speedup vs baseline: 1.0197x; 1.0197x over previous
//
#include <hip/hip_runtime.h>
#include <hip/hip_bf16.h>
#include <cstdint>

#define BB 64
#define NN 512
#define MM 1024
#define DD 128

typedef __bf16 bf16x8 __attribute__((ext_vector_type(8)));
typedef float f32x4 __attribute__((ext_vector_type(4)));

static __device__ __forceinline__ unsigned short f2bf(float f) {
    union { float f; unsigned int i; } v; v.f = f;
    unsigned int x = v.i;
    x += 0x7FFFu + ((x >> 16) & 1u);   // RNE
    return (unsigned short)(x >> 16);
}
// packed v_cvt_pk_bf16_f32: low = a, high = b
static __device__ __forceinline__ unsigned int f2bf2(float a, float b) {
    union { __hip_bfloat162 h; unsigned int u; } c;
    c.h = __float22bfloat162_rn(make_float2(a, b));
    return c.u;
}
// async global->LDS DMA, 16 B per lane, dest = wave-uniform base + lane*16
static __device__ __forceinline__ void async16(const void* g, void* l) {
    __builtin_amdgcn_global_load_lds(
        (const __attribute__((address_space(1))) void*)g,
        (__attribute__((address_space(3))) void*)l, 16, 0, 0);
}

// ---------- Kernel 1: merged projections (W converted IN-KERNEL) -------------
// Grid 1536: [0,1024) V-type: Vp = relu(h_p Wv^T + b) -> Vp tiles + VpT tiles.
// [1024,1536) C-type: Uc_scaled = relu(h_c Wu^T + b)*log2e (scale folded into
// the W/bias conversion) -> Ucg row-major bf16 + colsum f32.
// No wcvt kernel: the 2-block converter serialized the whole pipeline (~4 us
// on 2 CUs while 254 idle); redundant per-block conversion is fully parallel.
__global__ __launch_bounds__(256, 4) void proj_kernel(
    const float* __restrict__ hp,
    const float* __restrict__ hc,
    const float* __restrict__ Wu,
    const float* __restrict__ Wv,
    const float* __restrict__ Ub,
    const float* __restrict__ Vb,
    unsigned short* __restrict__ Y,           // Vp  (B,16,64,128)
    unsigned short* __restrict__ YT,          // VpT (B,16,128,64)
    unsigned short* __restrict__ Ucg,         // (B*512,128) bf16 row-major
    float* __restrict__ colsum)               // (B*8,128) f32
{
    __shared__ __align__(16) unsigned short Ws[128 * 136];   // 34816 B
    unsigned short* Ys = Ws;            // 64*128 shorts
    unsigned short* Ts = Ws + 8192;     // 128*72 shorts (V) / cs floats (C)
    const int t = threadIdx.x;
    const int lane = t & 63;
    const int wave = t >> 6;
    const int n16 = lane & 15, q = lane >> 4;
    const bool isC = blockIdx.x >= (BB * MM / 64);
    const float ws = isC ? 1.44269504088896f : 1.0f;   // log2(e) folded for C

    const long row0 = isC ? (long)(blockIdx.x - BB * MM / 64) * 64
                          : (long)blockIdx.x * 64;
    const float* X = isC ? hc : hp;
    const float* Wf = isC ? Wu : Wv;
    const float* bias = isC ? Ub : Vb;

    // X loads FIRST (latency overlaps W staging below)
    float4 xv[8];
    {
        const float* xrow = X + (row0 + wave * 16 + n16) * DD + q * 8;
        #pragma unroll
        for (int kk = 0; kk < 4; ++kk) {
            xv[2 * kk]     = *(const float4*)(xrow + kk * 32);
            xv[2 * kk + 1] = *(const float4*)(xrow + kk * 32 + 4);
        }
    }
    // stage W fp32 -> bf16 (scaled) into padded LDS
    {
        const float4* Wg = (const float4*)Wf;
        #pragma unroll
        for (int i = 0; i < 16; ++i) {
            int idx = i * 256 + t;            // 4096 float4
            float4 v = Wg[idx];
            int off = idx * 4;                // shorts
            uint2 u = { f2bf2(v.x * ws, v.y * ws), f2bf2(v.z * ws, v.w * ws) };
            *(uint2*)&Ws[(off >> 7) * 136 + (off & 127)] = u;
        }
    }
    __syncthreads();

    f32x4 acc[8];
    #pragma unroll
    for (int j = 0; j < 8; ++j) acc[j] = {0.f, 0.f, 0.f, 0.f};

    #pragma unroll
    for (int kk = 0; kk < 4; ++kk) {
        float4 x0 = xv[2 * kk], x1 = xv[2 * kk + 1];
        union { bf16x8 v; unsigned int u[4]; } a;
        a.u[0] = f2bf2(x0.x, x0.y); a.u[1] = f2bf2(x0.z, x0.w);
        a.u[2] = f2bf2(x1.x, x1.y); a.u[3] = f2bf2(x1.z, x1.w);
        #pragma unroll
        for (int j = 0; j < 8; ++j) {
            bf16x8 b = *(const bf16x8*)&Ws[(j * 16 + n16) * 136 + q * 8 + kk * 32];
            acc[j] = __builtin_amdgcn_mfma_f32_16x16x32_bf16(a.v, b, acc[j], 0, 0, 0);
        }
    }

    unsigned short yb[8][4];
    float colp[8];
    #pragma unroll
    for (int j = 0; j < 8; ++j) {
        const float bv = bias[j * 16 + n16] * ws;
        float y[4], s = 0.f;
        #pragma unroll
        for (int r = 0; r < 4; ++r) {
            float v = acc[j][r] + bv;
            v = v > 0.f ? v : 0.f;
            y[r] = v;
            s += v;
        }
        colp[j] = s;
        uint2 u = { f2bf2(y[0], y[1]), f2bf2(y[2], y[3]) };
        *(uint2*)&yb[j][0] = u;
    }
    __syncthreads();   // Ws reads done; reuse as Ys/Ts

    if (!isC) {
        #pragma unroll
        for (int j = 0; j < 8; ++j) {
            const int e = j * 16 + n16;
            #pragma unroll
            for (int r = 0; r < 4; ++r)
                Ys[(wave * 16 + q * 4 + r) * 128 + e] = yb[j][r];
            *(uint2*)&Ts[e * 72 + wave * 16 + q * 4] = *(uint2*)&yb[j][0];
        }
        __syncthreads();
        uint4* dstY = (uint4*)(Y + row0 * DD);
        const long b = row0 >> 10;
        const long mt = (row0 & 1023) >> 6;
        uint4* dstT = (uint4*)(YT + ((b * 16 + mt) * 128) * 64);
        #pragma unroll
        for (int i = 0; i < 4; ++i) {
            int idx = i * 256 + t;
            dstY[idx] = ((const uint4*)Ys)[idx];
            int e = idx >> 3, m = (idx & 7) * 8;
            dstT[idx] = *(const uint4*)&Ts[e * 72 + m];
        }
    } else {
        // column-sum: colp[j] covers rows (q,r) for col j*16+n16; reduce q
        #pragma unroll
        for (int j = 0; j < 8; ++j) {
            colp[j] += __shfl_xor(colp[j], 16);
            colp[j] += __shfl_xor(colp[j], 32);
        }
        float* cs = (float*)Ts;             // 512 floats
        if (q == 0) {
            #pragma unroll
            for (int j = 0; j < 8; ++j)
                cs[wave * 128 + j * 16 + n16] = colp[j];
        }
        #pragma unroll
        for (int j = 0; j < 8; ++j) {
            const int e = j * 16 + n16;
            #pragma unroll
            for (int r = 0; r < 4; ++r)
                Ys[(wave * 16 + q * 4 + r) * 128 + e] = yb[j][r];
        }
        __syncthreads();
        const int c = (int)(row0 >> 6);
        uint4* dstU = (uint4*)(Ucg + row0 * DD);
        #pragma unroll
        for (int i = 0; i < 4; ++i) {
            int idx = i * 256 + t;
            dstU[idx] = ((const uint4*)Ys)[idx];
        }
        if (t < 128)
            colsum[(long)c * DD + t] = cs[t] + cs[128 + t] + cs[256 + t] + cs[384 + t];
    }
}

// ---------- Kernel 2: bilinear attention, T15-reordered pipeline -------------
// Grid 512 (b,nt) XCD-swizzled; 4 waves; LDS 67584 B (grid caps occupancy at
// 2 blocks/CU; LDS < 80 KB is free).
//   buf0/1/2 [0,24576): VpT tile triple-buffer (DMA distance = 2 iterations)
//   Ps0 [24576,29184), Ps1 [29184,33792): double-buffered P exchange
// Iteration i body (ONE barrier, PV decoupled from this iter's softmax):
//   DMA(i+2) -> buf[(i+2)%3]; Apf(i+2) -> regs;
//   vmcnt(8)  (drains DMA(i+1)+Apf(i+1); leaves this iter's 8 in flight;
//              also guarantees own-DMA drain BEFORE the barrier that
//              publishes the buffer to other waves)
//   QK(i+1) from regs -> exp2 -> Ps[(i+1)&1]        (skipped when i==15)
//   PV(i)  from Ps[i&1] + buf[i%3]                   (reads pre-barrier data)
//   lgkmcnt(0); s_barrier                            (publishes Ps + buffers)
// Safety: PV(i) reads Ps written before barrier(i-1); QK writes parity i+1,
// the only same-parity reader (PV(i-1)) finished before barrier(i-1).
static __device__ __forceinline__ void attn_iter(
    int mt, unsigned short* bD, const unsigned short* bR,
    unsigned short* PsW, const unsigned short* PsR,
    const unsigned short* __restrict__ vpb,
    const unsigned short* __restrict__ vtb,
    int wave, int lane, int n16, int q, int a_off,
    const bf16x8 (&Bg)[4][4],
    bf16x8 (&aC)[4], bf16x8 (&aN)[4],
    f32x4 (&O)[8], float (&lpart)[4])
{
    const int nx = (mt + 2 > 15) ? 15 : mt + 2;   // clamp keeps vmcnt uniform
    // DMA VpT tile mt+2 (read in iteration mt+2: 2 full iters of cover)
    {
        const unsigned short* st = vtb + nx * 8192;
        unsigned short* dst = bD + wave * 2048;
        #pragma unroll
        for (int i = 0; i < 4; ++i) {
            int L = wave * 256 + i * 64 + lane;
            int r = L >> 3, sc = L & 7, c = sc ^ (r & 7);
            async16(st + r * 64 + c * 8, dst + i * 512);
        }
    }
    __builtin_amdgcn_sched_barrier(0);   // DMA issues before Apf (vmcnt order)
    // A-frag prefetch tile mt+2 (consumed by QK in iteration mt+1)
    {
        const unsigned short* pa = vpb + nx * 8192 + a_off;
        #pragma unroll
        for (int kk = 0; kk < 4; ++kk)
            aN[kk] = *(const bf16x8*)(pa + kk * 32);
    }
    // counted wait: 8 newest (this iter's DMA+Apf) stay in flight
    asm volatile("s_waitcnt vmcnt(8)" ::: "memory");
    __builtin_amdgcn_sched_barrier(0);

    if (mt < 15) {
        // QK(mt+1) m-split: S^T rows m = wave*16+q*4+r, cols n = j*16+n16
        f32x4 S[4];
        #pragma unroll
        for (int j = 0; j < 4; ++j) S[j] = {0.f, 0.f, 0.f, 0.f};
        __builtin_amdgcn_s_setprio(1);
        #pragma unroll
        for (int kk = 0; kk < 4; ++kk) {
            #pragma unroll
            for (int j = 0; j < 4; ++j)
                S[j] = __builtin_amdgcn_mfma_f32_16x16x32_bf16(aC[kk], Bg[j][kk], S[j], 0, 0, 0);
        }
        __builtin_amdgcn_s_setprio(0);
        // p = exp2(S) (Uc pre-scaled); write P[n][m] slices to PsW
        #pragma unroll
        for (int j = 0; j < 4; ++j) {
            float p0 = __builtin_exp2f(S[j][0]);
            float p1 = __builtin_exp2f(S[j][1]);
            float p2 = __builtin_exp2f(S[j][2]);
            float p3 = __builtin_exp2f(S[j][3]);
            lpart[j] += (p0 + p1) + (p2 + p3);
            uint2 u = { f2bf2(p0, p1), f2bf2(p2, p3) };
            *(uint2*)&PsW[(j * 16 + n16) * 72 + wave * 16 + q * 4] = u;
        }
    }

    // PV(mt) n-split: O[n][d] for this wave's 16 n-rows from PsR + bR
    __builtin_amdgcn_s_setprio(1);
    #pragma unroll
    for (int kk = 0; kk < 2; ++kk) {
        bf16x8 a = *(const bf16x8*)&PsR[(wave * 16 + n16) * 72 + kk * 32 + q * 8];
        #pragma unroll
        for (int j = 0; j < 8; ++j) {
            bf16x8 bb = *(const bf16x8*)&bR[(j * 16 + n16) * 64 + ((kk * 4 + q) ^ (n16 & 7)) * 8];
            O[j] = __builtin_amdgcn_mfma_f32_16x16x32_bf16(a, bb, O[j], 0, 0, 0);
        }
    }
    __builtin_amdgcn_s_setprio(0);
    // single barrier: publish Ps[(mt+1)&1] + buffer rotation
    asm volatile("s_waitcnt lgkmcnt(0)" ::: "memory");
    __builtin_amdgcn_s_barrier();
    __builtin_amdgcn_sched_barrier(0);
}

__global__ __launch_bounds__(256, 2) void attn_kernel(
    const unsigned short* __restrict__ Ucg,   // (B*512,128) bf16, pre-scaled
    const unsigned short* __restrict__ Vp,    // (B,16,64,128) bf16 tiled
    const unsigned short* __restrict__ VpT,   // (B,16,128,64) bf16 tiled
    float* __restrict__ part)                 // (B*8,128) fp32
{
    __shared__ __align__(16) unsigned short smem[33792];   // 67584 B
    unsigned short* Ps0 = smem + 24576;
    unsigned short* Ps1 = smem + 29184;

    const int t = threadIdx.x;
    const int lane = t & 63;
    const int wave = t >> 6;
    const int n16 = lane & 15, q = lane >> 4;

    const int id = blockIdx.x;
    const int xcd = id & 7;
    const int slot = id >> 3;
    const int b = xcd * 8 + (slot >> 3);
    const int nt = slot & 7;

    const unsigned short* vpb = Vp + (long)b * MM * DD;    // 16 tiles of 8192
    const unsigned short* vtb = VpT + (long)b * MM * DD;
    const unsigned short* ucb = Ucg + ((long)b * NN + nt * 64) * DD;

    // Prologue: Bg (all 64 Uc rows); Apf(0)->aA; DMA(0),DMA(1); Apf(1)->aB;
    // QK(0) -> Ps0; barrier.
    bf16x8 Bg[4][4];
    #pragma unroll
    for (int j = 0; j < 4; ++j)
        #pragma unroll
        for (int kk = 0; kk < 4; ++kk)
            Bg[j][kk] = *(const bf16x8*)&ucb[(j * 16 + n16) * 128 + kk * 32 + q * 8];

    const int a_off = (wave * 16 + n16) * 128 + q * 8;
    bf16x8 aA[4], aB[4];
    #pragma unroll
    for (int kk = 0; kk < 4; ++kk)
        aA[kk] = *(const bf16x8*)&vpb[a_off + kk * 32];
    #pragma unroll
    for (int tt = 0; tt < 2; ++tt) {
        const unsigned short* st = vtb + tt * 8192;
        unsigned short* dst = smem + tt * 8192 + wave * 2048;
        #pragma unroll
        for (int i = 0; i < 4; ++i) {
            int L = wave * 256 + i * 64 + lane;
            int r = L >> 3, sc = L & 7, c = sc ^ (r & 7);
            async16(st + r * 64 + c * 8, dst + i * 512);
        }
    }
    #pragma unroll
    for (int kk = 0; kk < 4; ++kk)
        aB[kk] = *(const bf16x8*)&vpb[8192 + a_off + kk * 32];

    float lpart[4] = {0.f, 0.f, 0.f, 0.f};
    {
        // QK(0) using aA (compiler waits for aA regs automatically)
        f32x4 S[4];
        #pragma unroll
        for (int j = 0; j < 4; ++j) S[j] = {0.f, 0.f, 0.f, 0.f};
        #pragma unroll
        for (int kk = 0; kk < 4; ++kk) {
            #pragma unroll
            for (int j = 0; j < 4; ++j)
                S[j] = __builtin_amdgcn_mfma_f32_16x16x32_bf16(aA[kk], Bg[j][kk], S[j], 0, 0, 0);
        }
        #pragma unroll
        for (int j = 0; j < 4; ++j) {
            float p0 = __builtin_exp2f(S[j][0]);
            float p1 = __builtin_exp2f(S[j][1]);
            float p2 = __builtin_exp2f(S[j][2]);
            float p3 = __builtin_exp2f(S[j][3]);
            lpart[j] += (p0 + p1) + (p2 + p3);
            uint2 u = { f2bf2(p0, p1), f2bf2(p2, p3) };
            *(uint2*)&Ps0[(j * 16 + n16) * 72 + wave * 16 + q * 4] = u;
        }
    }
    asm volatile("s_waitcnt lgkmcnt(0)" ::: "memory");
    __builtin_amdgcn_s_barrier();
    __builtin_amdgcn_sched_barrier(0);

    // ---- Main loop ----
    f32x4 O[8];
    #pragma unroll
    for (int j = 0; j < 8; ++j) O[j] = {0.f, 0.f, 0.f, 0.f};

    unsigned short* b0 = smem;            // buf[mt%3]     : PV source
    unsigned short* b1 = smem + 8192;     // buf[(mt+1)%3]
    unsigned short* b2 = smem + 16384;    // buf[(mt+2)%3] : DMA target
    #pragma unroll 1
    for (int mt = 0; mt < 16; mt += 2) {
        // iter mt: QK(mt+1) uses aB (tile mt+1), Apf(mt+2)->aA
        attn_iter(mt,     b2, b0, Ps1, Ps0, vpb, vtb, wave, lane, n16, q, a_off, Bg, aB, aA, O, lpart);
        // iter mt+1: QK(mt+2) uses aA, Apf(mt+3)->aB; bR=b1, bD=b0
        attn_iter(mt + 1, b0, b1, Ps0, Ps1, vpb, vtb, wave, lane, n16, q, a_off, Bg, aA, aB, O, lpart);
        unsigned short* tp = b0; b0 = b2; b2 = b1; b1 = tp;   // (b0,b1,b2)<-(b2,b0,b1)
    }

    // ---- Epilogue: l reduction + weighted O reduction (Ps0 is free) ----
    #pragma unroll
    for (int j = 0; j < 4; ++j) {
        lpart[j] += __shfl_xor(lpart[j], 16);
        lpart[j] += __shfl_xor(lpart[j], 32);
    }
    float* lred = (float*)Ps0;              // 256 floats
    float* red  = lred + 256;               // 512 floats
    if (q == 0) {
        #pragma unroll
        for (int j = 0; j < 4; ++j)
            lred[wave * 64 + j * 16 + n16] = lpart[j];
    }
    __syncthreads();

    float inv[4];
    #pragma unroll
    for (int r = 0; r < 4; ++r) {
        int n = wave * 16 + q * 4 + r;
        inv[r] = 1.0f / (lred[n] + lred[64 + n] + lred[128 + n] + lred[192 + n]);
    }

    #pragma unroll
    for (int j = 0; j < 8; ++j) {
        float s = O[j][0] * inv[0] + O[j][1] * inv[1]
                + O[j][2] * inv[2] + O[j][3] * inv[3];
        s += __shfl_xor(s, 16);
        s += __shfl_xor(s, 32);
        if (q == 0)
            red[wave * 128 + j * 16 + n16] = s;
    }
    __syncthreads();
    if (t < 128) {
        float tot = red[t] + red[128 + t] + red[256 + t] + red[384 + t];
        part[(long)(b * 8 + nt) * DD + t] = tot;
    }
}

// ---------- Kernel 3: out = (Sigma part + RLN2*Sigma colsum) * q / N ---------
__global__ __launch_bounds__(256) void finalize_kernel(
    const float* __restrict__ part, const float* __restrict__ colsum,
    const float* __restrict__ qv, float* __restrict__ out)
{
    int i = blockIdx.x * 256 + threadIdx.x;     // 8192
    int b = i >> 7, d = i & 127;
    const float* p  = part   + (long)b * 8 * DD + d;
    const float* cs = colsum + (long)b * 8 * DD + d;
    float s = 0.f, u = 0.f;
    #pragma unroll
    for (int nt = 0; nt < 8; ++nt) { s += p[nt * DD]; u += cs[nt * DD]; }
    out[i] = (s + u * 0.69314718055994531f) * qv[d] * (1.0f / (float)NN);
}

extern "C" void kernel_launch(void* const* d_in, const int* in_sizes, int n_in,
                              void* d_out, int out_size, void* d_ws, size_t ws_size,
                              hipStream_t stream) {
    const float* h_c = (const float*)d_in[0];
    const float* h_p = (const float*)d_in[1];
    const float* U_w = (const float*)d_in[2];
    const float* U_b = (const float*)d_in[3];
    const float* V_w = (const float*)d_in[4];
    const float* V_b = (const float*)d_in[5];
    const float* qv  = (const float*)d_in[6];
    float* out = (float*)d_out;

    unsigned short* Vp  = (unsigned short*)d_ws;                 // (B,16,64,128) bf16
    unsigned short* VpT = Vp + (size_t)BB * MM * DD;             // (B,16,128,64) bf16
    unsigned short* Ucg = VpT + (size_t)BB * MM * DD;            // (B*512,128) bf16
    float* part   = (float*)(Ucg + (size_t)BB * NN * DD);        // (B*8,128) fp32
    float* colsum = part + (size_t)BB * 8 * DD;                  // (B*8,128) fp32

    proj_kernel<<<BB * MM / 64 + BB * NN / 64, 256, 0, stream>>>(
        h_p, h_c, U_w, V_w, U_b, V_b, Vp, VpT, Ucg, colsum);
    attn_kernel<<<512, 256, 0, stream>>>(Ucg, Vp, VpT, part);
    finalize_kernel<<<32, 256, 0, stream>>>(part, colsum, qv, out);
}

// Round 8
// 136.202 us; speedup vs baseline: 1.0404x; 1.0202x over previous
//
#include <hip/hip_runtime.h>
#include <hip/hip_bf16.h>
#include <cstdint>

#define BB 64
#define NN 512
#define MM 1024
#define DD 128

typedef __bf16 bf16x8 __attribute__((ext_vector_type(8)));
typedef float f32x4 __attribute__((ext_vector_type(4)));
typedef short s16x4 __attribute__((ext_vector_type(4)));

static __device__ __forceinline__ unsigned short f2bf(float f) {
    union { float f; unsigned int i; } v; v.f = f;
    unsigned int x = v.i;
    x += 0x7FFFu + ((x >> 16) & 1u);   // RNE
    return (unsigned short)(x >> 16);
}
// packed v_cvt_pk_bf16_f32: low = a, high = b
static __device__ __forceinline__ unsigned int f2bf2(float a, float b) {
    union { __hip_bfloat162 h; unsigned int u; } c;
    c.h = __float22bfloat162_rn(make_float2(a, b));
    return c.u;
}
// async global->LDS DMA, 16 B per lane, dest = wave-uniform base + lane*16
static __device__ __forceinline__ void async16(const void* g, void* l) {
    __builtin_amdgcn_global_load_lds(
        (const __attribute__((address_space(1))) void*)g,
        (__attribute__((address_space(3))) void*)l, 16, 0, 0);
}

// ---------- Kernel 1: merged projections (W converted IN-KERNEL) -------------
// Grid 1536: [0,1024) V-type: Vp = relu(h_p Wv^T + b) -> Vp tiles (rows stored
// PRE-SWIZZLED: col e of row r lands at ((e>>3 ^ (r&7))<<3)|(e&7), so attn's
// linear global_load_lds lands an XOR-swizzled, conflict-free LDS tile) + VpT
// tiles (unswizzled; attn's DMA swizzles via source addressing, as before).
// [1024,1536) C-type: Uc_scaled = relu(h_c Wu^T + b)*log2e -> Ucg (LINEAR
// row-major, read directly as reg frags) + colsum f32.
__global__ __launch_bounds__(256, 4) void proj_kernel(
    const float* __restrict__ hp,
    const float* __restrict__ hc,
    const float* __restrict__ Wu,
    const float* __restrict__ Wv,
    const float* __restrict__ Ub,
    const float* __restrict__ Vb,
    unsigned short* __restrict__ Y,           // Vp  (B,16,64,128) swizzled rows
    unsigned short* __restrict__ YT,          // VpT (B,16,128,64)
    unsigned short* __restrict__ Ucg,         // (B*512,128) bf16 row-major
    float* __restrict__ colsum)               // (B*8,128) f32
{
    __shared__ __align__(16) unsigned short Ws[128 * 136];   // 34816 B
    unsigned short* Ys = Ws;            // 64*128 shorts
    unsigned short* Ts = Ws + 8192;     // 128*72 shorts (V) / cs floats (C)
    const int t = threadIdx.x;
    const int lane = t & 63;
    const int wave = t >> 6;
    const int n16 = lane & 15, q = lane >> 4;
    const bool isC = blockIdx.x >= (BB * MM / 64);
    const float ws = isC ? 1.44269504088896f : 1.0f;   // log2(e) folded for C

    const long row0 = isC ? (long)(blockIdx.x - BB * MM / 64) * 64
                          : (long)blockIdx.x * 64;
    const float* X = isC ? hc : hp;
    const float* Wf = isC ? Wu : Wv;
    const float* bias = isC ? Ub : Vb;

    // X loads FIRST (latency overlaps W staging below)
    float4 xv[8];
    {
        const float* xrow = X + (row0 + wave * 16 + n16) * DD + q * 8;
        #pragma unroll
        for (int kk = 0; kk < 4; ++kk) {
            xv[2 * kk]     = *(const float4*)(xrow + kk * 32);
            xv[2 * kk + 1] = *(const float4*)(xrow + kk * 32 + 4);
        }
    }
    // stage W fp32 -> bf16 (scaled) into padded LDS
    {
        const float4* Wg = (const float4*)Wf;
        #pragma unroll
        for (int i = 0; i < 16; ++i) {
            int idx = i * 256 + t;            // 4096 float4
            float4 v = Wg[idx];
            int off = idx * 4;                // shorts
            uint2 u = { f2bf2(v.x * ws, v.y * ws), f2bf2(v.z * ws, v.w * ws) };
            *(uint2*)&Ws[(off >> 7) * 136 + (off & 127)] = u;
        }
    }
    __syncthreads();

    f32x4 acc[8];
    #pragma unroll
    for (int j = 0; j < 8; ++j) acc[j] = {0.f, 0.f, 0.f, 0.f};

    #pragma unroll
    for (int kk = 0; kk < 4; ++kk) {
        float4 x0 = xv[2 * kk], x1 = xv[2 * kk + 1];
        union { bf16x8 v; unsigned int u[4]; } a;
        a.u[0] = f2bf2(x0.x, x0.y); a.u[1] = f2bf2(x0.z, x0.w);
        a.u[2] = f2bf2(x1.x, x1.y); a.u[3] = f2bf2(x1.z, x1.w);
        #pragma unroll
        for (int j = 0; j < 8; ++j) {
            bf16x8 b = *(const bf16x8*)&Ws[(j * 16 + n16) * 136 + q * 8 + kk * 32];
            acc[j] = __builtin_amdgcn_mfma_f32_16x16x32_bf16(a.v, b, acc[j], 0, 0, 0);
        }
    }

    unsigned short yb[8][4];
    float colp[8];
    #pragma unroll
    for (int j = 0; j < 8; ++j) {
        const float bv = bias[j * 16 + n16] * ws;
        float y[4], s = 0.f;
        #pragma unroll
        for (int r = 0; r < 4; ++r) {
            float v = acc[j][r] + bv;
            v = v > 0.f ? v : 0.f;
            y[r] = v;
            s += v;
        }
        colp[j] = s;
        uint2 u = { f2bf2(y[0], y[1]), f2bf2(y[2], y[3]) };
        *(uint2*)&yb[j][0] = u;
    }
    __syncthreads();   // Ws reads done; reuse as Ys/Ts

    if (!isC) {
        #pragma unroll
        for (int j = 0; j < 8; ++j) {
            const int e = j * 16 + n16;
            const int ehi = e >> 3, elo = e & 7;
            #pragma unroll
            for (int r = 0; r < 4; ++r) {
                int row = wave * 16 + q * 4 + r;
                // PRE-SWIZZLED store: attn DMAs this row linearly into LDS
                Ys[row * 128 + ((ehi ^ (row & 7)) << 3) + elo] = yb[j][r];
            }
            *(uint2*)&Ts[e * 72 + wave * 16 + q * 4] = *(uint2*)&yb[j][0];
        }
        __syncthreads();
        uint4* dstY = (uint4*)(Y + row0 * DD);
        const long b = row0 >> 10;
        const long mt = (row0 & 1023) >> 6;
        uint4* dstT = (uint4*)(YT + ((b * 16 + mt) * 128) * 64);
        #pragma unroll
        for (int i = 0; i < 4; ++i) {
            int idx = i * 256 + t;
            dstY[idx] = ((const uint4*)Ys)[idx];
            int e = idx >> 3, m = (idx & 7) * 8;
            dstT[idx] = *(const uint4*)&Ts[e * 72 + m];
        }
    } else {
        // column-sum: colp[j] covers rows (q,r) for col j*16+n16; reduce q
        #pragma unroll
        for (int j = 0; j < 8; ++j) {
            colp[j] += __shfl_xor(colp[j], 16);
            colp[j] += __shfl_xor(colp[j], 32);
        }
        float* cs = (float*)Ts;             // 512 floats
        if (q == 0) {
            #pragma unroll
            for (int j = 0; j < 8; ++j)
                cs[wave * 128 + j * 16 + n16] = colp[j];
        }
        #pragma unroll
        for (int j = 0; j < 8; ++j) {
            const int e = j * 16 + n16;
            #pragma unroll
            for (int r = 0; r < 4; ++r)
                Ys[(wave * 16 + q * 4 + r) * 128 + e] = yb[j][r];
        }
        __syncthreads();
        const int c = (int)(row0 >> 6);
        uint4* dstU = (uint4*)(Ucg + row0 * DD);
        #pragma unroll
        for (int i = 0; i < 4; ++i) {
            int idx = i * 256 + t;
            dstU[idx] = ((const uint4*)Ys)[idx];
        }
        if (t < 128)
            colsum[(long)c * DD + t] = cs[t] + cs[128 + t] + cs[256 + t] + cs[384 + t];
    }
}

// ---------- Kernel 2: EXCHANGE-FREE bilinear attention -----------------------
// Grid 512 (b,nt) XCD-swizzled; 4 waves; LDS 65536 B (2 blocks/CU).
//   bufV[2] [0,16384): Vp tile double-buffer (swizzled rows, linear DMA)
//   bufT[2] [16384,32768): VpT tile double-buffer (source-swizzled DMA)
// Per wave w: owns n-rows w*16+n16 (B = 4 Uc reg frags, loaded once).
//  QK: S[m][n-own]: A = Vp rows (all 64 m) from LDS, B = Bn.  Output lane
//  (n16,q) reg r: S[m=mtile*16+q*4+r][n=w*16+n16].
//  exp2 -> P: EXACTLY the A-frag of mfma_f32_16x16x16bf16_1k (lane holds
//  A[row=n16->n][k=q*4+e->m]) -- layout harness-verified in round 1.
//  PV: 4 mtiles x 8 dj, K=16; B = VpT[d][m-4span] b64 from LDS.
//  O[n-own][d] = 32 VGPR.  NO P exchange, NO Ps, ONE barrier/iter (DMA
//  publish only); waves otherwise independent.
// Iter: [DMA(mt+1) post-barrier -> parity buf; QK; exp2/pack; PV;
//        vmcnt(0) lgkm(0); s_barrier].  DMA target parity was last read in
//  iter mt-1, whose reads drained at barrier(mt-1) before this issue.
__global__ __launch_bounds__(256, 2) void attn_kernel(
    const unsigned short* __restrict__ Ucg,   // (B*512,128) bf16, pre-scaled
    const unsigned short* __restrict__ Vp,    // (B,16,64,128) swizzled rows
    const unsigned short* __restrict__ VpT,   // (B,16,128,64) bf16 tiled
    float* __restrict__ part)                 // (B*8,128) fp32
{
    __shared__ __align__(16) unsigned short smem[32768];   // 65536 B

    const int t = threadIdx.x;
    const int lane = t & 63;
    const int wave = t >> 6;
    const int n16 = lane & 15, q = lane >> 4;

    const int id = blockIdx.x;
    const int xcd = id & 7;
    const int slot = id >> 3;
    const int b = xcd * 8 + (slot >> 3);
    const int nt = slot & 7;

    const unsigned short* vpb = Vp + (long)b * MM * DD;    // 16 tiles of 8192
    const unsigned short* vtb = VpT + (long)b * MM * DD;
    const unsigned short* ucb = Ucg + ((long)b * NN + nt * 64) * DD;

    // B-frags: the wave's own 16 n-rows of Uc (16 VGPR, live all iterations)
    bf16x8 Bn[4];
    #pragma unroll
    for (int kk = 0; kk < 4; ++kk)
        Bn[kk] = *(const bf16x8*)&ucb[(wave * 16 + n16) * 128 + kk * 32 + q * 8];

    // Prologue: DMA tile 0 (Vp linear — global pre-swizzled; VpT src-swizzled)
    {
        #pragma unroll
        for (int i = 0; i < 4; ++i) {
            int L = wave * 256 + i * 64 + lane;
            async16(vpb + L * 8, smem + wave * 2048 + i * 512);
        }
        #pragma unroll
        for (int i = 0; i < 4; ++i) {
            int L = wave * 256 + i * 64 + lane;
            int r = L >> 3, sc = L & 7, c = sc ^ (r & 7);
            async16(vtb + r * 64 + c * 8, smem + 16384 + wave * 2048 + i * 512);
        }
    }
    asm volatile("s_waitcnt vmcnt(0) lgkmcnt(0)" ::: "memory");
    __builtin_amdgcn_s_barrier();
    __builtin_amdgcn_sched_barrier(0);

    f32x4 O[8];
    #pragma unroll
    for (int j = 0; j < 8; ++j) O[j] = {0.f, 0.f, 0.f, 0.f};
    float lsum = 0.f;

    #pragma unroll 1
    for (int mt = 0; mt < 16; ++mt) {
        const unsigned short* V  = (mt & 1) ? smem + 8192  : smem;
        const unsigned short* VT = (mt & 1) ? smem + 24576 : smem + 16384;
        // DMA tile mt+1 into the other parity (safe: that parity's readers
        // drained at barrier(mt-1); we are past it)
        if (mt < 15) {
            const unsigned short* sv = vpb + (mt + 1) * 8192;
            const unsigned short* st = vtb + (mt + 1) * 8192;
            unsigned short* dv = ((mt & 1) ? smem : smem + 8192) + wave * 2048;
            unsigned short* dt = ((mt & 1) ? smem + 16384 : smem + 24576) + wave * 2048;
            #pragma unroll
            for (int i = 0; i < 4; ++i) {
                int L = wave * 256 + i * 64 + lane;
                async16(sv + L * 8, dv + i * 512);
            }
            #pragma unroll
            for (int i = 0; i < 4; ++i) {
                int L = wave * 256 + i * 64 + lane;
                int r = L >> 3, sc = L & 7, c = sc ^ (r & 7);
                async16(st + r * 64 + c * 8, dt + i * 512);
            }
        }
        __builtin_amdgcn_sched_barrier(0);

        // QK: S[mtile] over all 64 m, own 16 n.  A from swizzled LDS rows.
        f32x4 S[4];
        #pragma unroll
        for (int j = 0; j < 4; ++j) S[j] = {0.f, 0.f, 0.f, 0.f};
        __builtin_amdgcn_s_setprio(1);
        #pragma unroll
        for (int mtile = 0; mtile < 4; ++mtile) {
            const int m = mtile * 16 + n16;
            #pragma unroll
            for (int kk = 0; kk < 4; ++kk) {
                bf16x8 a = *(const bf16x8*)&V[m * 128 + (((kk * 4 + q) ^ (m & 7)) << 3)];
                S[mtile] = __builtin_amdgcn_mfma_f32_16x16x32_bf16(a, Bn[kk], S[mtile], 0, 0, 0);
            }
        }
        __builtin_amdgcn_s_setprio(0);

        // p = exp2(S); pack DIRECTLY into K=16 PV A-frags (lane-local!)
        s16x4 av[4];
        #pragma unroll
        for (int j = 0; j < 4; ++j) {
            float p0 = __builtin_exp2f(S[j][0]);
            float p1 = __builtin_exp2f(S[j][1]);
            float p2 = __builtin_exp2f(S[j][2]);
            float p3 = __builtin_exp2f(S[j][3]);
            lsum += (p0 + p1) + (p2 + p3);
            union { unsigned int u[2]; s16x4 v; } pk;
            pk.u[0] = f2bf2(p0, p1); pk.u[1] = f2bf2(p2, p3);
            av[j] = pk.v;
        }

        // PV: O[n-own][d] += P[n][m-chunk] * V[m-chunk][d], K=16 per mtile.
        // B-frag: VT[d = dj*16+n16][m = mtile*16 + q*4 .. +3] (b64, swizzled).
        __builtin_amdgcn_s_setprio(1);
        #pragma unroll
        for (int mtile = 0; mtile < 4; ++mtile) {
            #pragma unroll
            for (int dj = 0; dj < 8; ++dj) {
                const int d = dj * 16 + n16;
                s16x4 bv = *(const s16x4*)&VT[d * 64
                    + (((mtile * 2 + (q >> 1)) ^ (d & 7)) << 3) + ((q & 1) << 2)];
                O[dj] = __builtin_amdgcn_mfma_f32_16x16x16bf16_1k(av[mtile], bv, O[dj], 0, 0, 0);
            }
        }
        __builtin_amdgcn_s_setprio(0);

        // publish: own ds_reads done + own DMA landed; barrier releases bufs
        asm volatile("s_waitcnt vmcnt(0) lgkmcnt(0)" ::: "memory");
        __builtin_amdgcn_s_barrier();
        __builtin_amdgcn_sched_barrier(0);
    }

    // ---- Epilogue ----
    // lsum: n = w*16+n16 is lane-local; reduce over q -> full row sum
    lsum += __shfl_xor(lsum, 16);
    lsum += __shfl_xor(lsum, 32);
    float* scr  = (float*)smem;          // buffers dead after final barrier
    float* invw = scr + wave * 16;       // per-wave 16 floats (wave-private)
    if (lane < 16) invw[n16] = 1.0f / lsum;
    // wave-internal ds_write->ds_read: in-order, compiler inserts lgkmcnt
    float iv[4];
    #pragma unroll
    for (int r = 0; r < 4; ++r) iv[r] = invw[q * 4 + r];

    float* red = scr + 64;               // 512 floats
    #pragma unroll
    for (int dj = 0; dj < 8; ++dj) {
        float s = O[dj][0] * iv[0] + O[dj][1] * iv[1]
                + O[dj][2] * iv[2] + O[dj][3] * iv[3];
        s += __shfl_xor(s, 16);
        s += __shfl_xor(s, 32);
        if (q == 0)
            red[wave * 128 + dj * 16 + n16] = s;
    }
    __syncthreads();
    if (t < 128) {
        float tot = red[t] + red[128 + t] + red[256 + t] + red[384 + t];
        part[(long)(b * 8 + nt) * DD + t] = tot;
    }
}

// ---------- Kernel 3: out = (Sigma part + RLN2*Sigma colsum) * q / N ---------
__global__ __launch_bounds__(256) void finalize_kernel(
    const float* __restrict__ part, const float* __restrict__ colsum,
    const float* __restrict__ qv, float* __restrict__ out)
{
    int i = blockIdx.x * 256 + threadIdx.x;     // 8192
    int b = i >> 7, d = i & 127;
    const float* p  = part   + (long)b * 8 * DD + d;
    const float* cs = colsum + (long)b * 8 * DD + d;
    float s = 0.f, u = 0.f;
    #pragma unroll
    for (int nt = 0; nt < 8; ++nt) { s += p[nt * DD]; u += cs[nt * DD]; }
    out[i] = (s + u * 0.69314718055994531f) * qv[d] * (1.0f / (float)NN);
}

extern "C" void kernel_launch(void* const* d_in, const int* in_sizes, int n_in,
                              void* d_out, int out_size, void* d_ws, size_t ws_size,
                              hipStream_t stream) {
    const float* h_c = (const float*)d_in[0];
    const float* h_p = (const float*)d_in[1];
    const float* U_w = (const float*)d_in[2];
    const float* U_b = (const float*)d_in[3];
    const float* V_w = (const float*)d_in[4];
    const float* V_b = (const float*)d_in[5];
    const float* qv  = (const float*)d_in[6];
    float* out = (float*)d_out;

    unsigned short* Vp  = (unsigned short*)d_ws;                 // (B,16,64,128) bf16 swz
    unsigned short* VpT = Vp + (size_t)BB * MM * DD;             // (B,16,128,64) bf16
    unsigned short* Ucg = VpT + (size_t)BB * MM * DD;            // (B*512,128) bf16
    float* part   = (float*)(Ucg + (size_t)BB * NN * DD);        // (B*8,128) fp32
    float* colsum = part + (size_t)BB * 8 * DD;                  // (B*8,128) fp32

    proj_kernel<<<BB * MM / 64 + BB * NN / 64, 256, 0, stream>>>(
        h_p, h_c, U_w, V_w, U_b, V_b, Vp, VpT, Ucg, colsum);
    attn_kernel<<<512, 256, 0, stream>>>(Ucg, Vp, VpT, part);
    finalize_kernel<<<32, 256, 0, stream>>>(part, colsum, qv, out);
}